// Round 10
// baseline (47.583 us; speedup 1.0000x reference)
//
#include <hip/hip_runtime.h>
#include <stdint.h>
#include <limits.h>

// ---------------------------------------------------------------------------
// GeToInformedNeighborSampler — round 10 (fuse to 2 kernels + memset node).
//
// Exact clip-aware reduction (validated rounds 5-9, absmax 0):
//   A = max_{j<D} v_j, a = first argmax   (v_j = gumbel(s*NC+j) + logp[j])
//   r[s] = (exists j in [D,NC): v_j > A) ? D-1 : a
//
// Round-9 standing: witness scan with per-sample padded flag (private 256B
// line), plain gated AGENT store, per-round poll-abort — 47us total, but
// ~25-30us of that is 4 serialized kernel nodes' launch/gap overhead.
// This round: 3 nodes total.
//   node 1: hipMemsetAsync(wflag, 0)        — every-call zero (replay-safe)
//   node 2: decide_kernel                   — phase A inlined per wave
//            (j<D => b=0 => one ids-row; each wave recomputes A/kb in regs,
//             no LDS/sync; block (0,s) stores aidx[s]); then the r9 witness
//             scan, unchanged.
//   node 3: gather_kernel                   — select folded in
//            (r = wflag ? D-1 : aidx, clamped), then the output gather.
//
// Flag determinism: set only on a true witness; abort only when already 1
// => final flag == [exists witness] exactly; memset makes every call start
// from 0 (no cross-call state).
// RNG (threefry2x32 key (0,42), classic split, o0-only) + raw-bits prune
// filter kb(A): unchanged (absmax 0, 8 consecutive rounds).
// All cross-kernel handoffs AGENT-scope (G16).
// ---------------------------------------------------------------------------

#define DEVI __device__ __forceinline__

DEVI uint32_t rotl32(uint32_t x, int n) { return (x << n) | (x >> (32 - n)); }

// threefry2x32-20, key (0,42), o0 only. x1 must already include +K1 (=42).
DEVI uint32_t tf_o0p(uint32_t x0, uint32_t x1) {
  const uint32_t K1 = 42u;
  const uint32_t K2 = 0x1BD11BDAu ^ K1;  // K0 = 0
#define TFR(r) x0 += x1; x1 = rotl32(x1, (r)); x1 ^= x0;
  TFR(13) TFR(15) TFR(26) TFR(6)
  x0 += K1; x1 += K2 + 1u;
  TFR(17) TFR(29) TFR(16) TFR(24)
  x0 += K2; x1 += 2u;                    // + K0 + 2
  TFR(13) TFR(15) TFR(26) TFR(6)
  /* x0 += K0 */ x1 += K1 + 3u;
  TFR(17) TFR(29) TFR(16) TFR(24)
  x0 += K1; x1 += K2 + 4u;
  TFR(13) TFR(15) TFR(26)
  x0 += x1;                              // round 20: only the add feeds o0
  x0 += K2;                              // final injection for o0
#undef TFR
  return x0;
}

DEVI uint32_t ld_dev_u32(const uint32_t* p) {
  return __hip_atomic_load(p, __ATOMIC_RELAXED, __HIP_MEMORY_SCOPE_AGENT);
}
DEVI void st_dev_u32(uint32_t* p, uint32_t v) {
  __hip_atomic_store(p, v, __ATOMIC_RELAXED, __HIP_MEMORY_SCOPE_AGENT);
}

// Raw-bits prune threshold: all j with g_j > m satisfy bits >= kb(m).
DEVI uint32_t prune_kb(float m) {
  float t = expf(-expf(-m)) - 1e-5f;
  if (!(t > 0.0f)) return 0u;
  uint32_t k = (uint32_t)ceilf(t * 8388608.0f);
  if (k > 8388607u) k = 8388607u;
  return k << 9;
}

// Exact JAX gumbel+logit value of element j of one sample.
DEVI float eval_v(uint32_t bits, uint32_t j,
                  const int* __restrict__ ids, const int* __restrict__ geto,
                  const float* __restrict__ probs, int D, int dlog) {
  float u = __uint_as_float((bits >> 9) | 0x3f800000u) - 1.0f;
  u = fmaxf(u, 1.17549435e-38f);
  float g = -logf(-logf(u));
  uint32_t b, d;
  if (dlog >= 0) { b = j >> dlog; d = j & (uint32_t)(D - 1); }
  else { b = j / (uint32_t)D; d = j - b * (uint32_t)D; }
  float lp = logf(probs[geto[(uint32_t)ids[b] * (uint32_t)D + d]]);
  return g + lp;
}

// ---- K1: fused decide (inline phase A + witness scan with abort) ----------
__global__ __launch_bounds__(256) void decide_kernel(
    const int* __restrict__ ids, const int* __restrict__ geto,
    const float* __restrict__ probs,
    uint32_t* __restrict__ aidx, uint32_t* __restrict__ wflag,
    int NC, int D, int dlog, uint32_t dcK, int wwin, int WV) {
  const int s = blockIdx.y;
  const int wv = blockIdx.x * 4 + (threadIdx.x >> 6);   // wave-window id
  const int lane = threadIdx.x & 63;
  const uint32_t sbase = (uint32_t)s * (uint32_t)NC;
  uint32_t* flagp = &wflag[s * 64];

  // Phase A, per-wave redundant (j<D => b=0 => one ids-row; loads broadcast/
  // cached). No LDS, no __syncthreads.
  float av = -INFINITY;
  int ai = INT_MAX;
  for (uint32_t j = (uint32_t)lane; j < (uint32_t)D; j += 64u) {
    uint32_t cc = sbase + j;
    float v = eval_v(tf_o0p(cc, cc + dcK), j, ids, geto, probs, D, dlog);
    if (v > av) { av = v; ai = (int)j; }   // ascending j: > keeps first
  }
  for (int off = 32; off > 0; off >>= 1) {
    float v2 = __shfl_xor(av, off);
    int i2 = __shfl_xor(ai, off);
    if (v2 > av || (v2 == av && i2 < ai)) { av = v2; ai = i2; }
  }
  const float A = av;
  const uint32_t kb = prune_kb(A);
  if (blockIdx.x == 0 && threadIdx.x == 0)
    st_dev_u32(&aidx[s], (uint32_t)ai);

  if (wv >= WV) return;
  uint32_t wstart = (uint32_t)D + (uint32_t)wv * (uint32_t)wwin;
  uint32_t wend = wstart + (uint32_t)wwin;
  if (wend > (uint32_t)NC) wend = (uint32_t)NC;

  for (uint32_t base = wstart; base < wend; base += 512u) {
    // Poll issued early (independent load), consumed at round end.
    uint32_t poll = 0u;
    if (lane == 0) poll = ld_dev_u32(flagp);

    uint32_t a[8];
    uint32_t bb = 0u, bj = 0xFFFFFFFFu;  // per-lane best passer
    bool anyok = false;
#pragma unroll
    for (int c = 0; c < 8; ++c) {
      uint32_t j = base + (uint32_t)(c * 64) + (uint32_t)lane;
      uint32_t cc = sbase + j;
      uint32_t bits = tf_o0p(cc, cc + dcK);
      a[c] = bits;
      bool ok = (bits >= kb) && (j < wend);
      if (ok) { anyok = true; if (bits > bb || bj == 0xFFFFFFFFu) { bb = bits; bj = j; } }
    }

    bool found = false;
    if (__any(anyok)) {
      // wave-reduce best candidate (max bits; index tie-break, deterministic)
      for (int off = 32; off > 0; off >>= 1) {
        uint32_t ob = __shfl_xor(bb, off);
        uint32_t oj = __shfl_xor(bj, off);
        bool better = (oj != 0xFFFFFFFFu) &&
                      (bj == 0xFFFFFFFFu || ob > bb || (ob == bb && oj < bj));
        if (better) { bb = ob; bj = oj; }
      }
      // Evaluate best candidate wave-uniform (broadcast loads, one chain).
      float v = eval_v(bb, bj, ids, geto, probs, D, dlog);
      if (v > A) {
        found = true;
      } else {
        // Rare fallback: evaluate every passer (exact round OR preserved).
#pragma unroll
        for (int c = 0; c < 8; ++c) {
          uint32_t j = base + (uint32_t)(c * 64) + (uint32_t)lane;
          if (a[c] >= kb && j < wend && j != bj) {
            if (eval_v(a[c], j, ids, geto, probs, D, dlog) > A) found = true;
          }
        }
      }
    }
    uint32_t p0 = (uint32_t)__shfl((int)poll, 0);
    if (__any(found)) {
      // plain agent store, gated: p0==1 => flag already 1 (monotonic), skip.
      if (lane == 0 && p0 == 0u) st_dev_u32(flagp, 1u);
      return;
    }
    if (p0) return;                      // someone already proved existence
  }
}

// ---- K2: select + gather outputs ------------------------------------------
__global__ __launch_bounds__(256) void gather_kernel(
    const int* __restrict__ ids, const int* __restrict__ adj,
    const int* __restrict__ geto,
    const uint32_t* __restrict__ aidx, const uint32_t* __restrict__ wflag,
    int* __restrict__ out, int B, int D, int ns) {
  __shared__ int sr[64];
  if (threadIdx.x < ns) {
    int s = threadIdx.x;
    int r = ld_dev_u32(&wflag[s * 64]) ? (D - 1) : (int)ld_dev_u32(&aidx[s]);
    r = r < 0 ? 0 : (r > D - 1 ? D - 1 : r);   // take(..., mode='clip')
    sr[s] = r;
  }
  __syncthreads();
  int t = blockIdx.x * blockDim.x + threadIdx.x;
  int total = B * ns;
  if (t >= total) return;
  int b = t / ns;
  int s = t - b * ns;
  int r = sr[s];
  int row = ids[b];
  out[t] = adj[row * D + r];            // weighted_adj[:, :ns]
  out[total + t] = geto[row * D + r];   // weighted_geto[:, :ns]
}

// ---------------------------------------------------------------------------
extern "C" void kernel_launch(void* const* d_in, const int* in_sizes, int n_in,
                              void* d_out, int out_size, void* d_ws, size_t ws_size,
                              hipStream_t stream) {
  const int* ids = (const int*)d_in[0];
  const int* adj = (const int*)d_in[2];
  const int* geto = (const int*)d_in[3];
  const float* probs = (const float*)d_in[4];
  int* out = (int*)d_out;

  const int B = in_sizes[0];             // 100000
  const int D = in_sizes[2] / B;         // 64
  const int NC = B * D;                  // 6.4M categories
  const int S = D;                       // 64 total samples (RESAMPLING_RATE=0)
  const int ns = out_size / (2 * B);     // 25 — only these are consumed
  const uint32_t dc = (uint32_t)(S / 2) * (uint32_t)NC;  // classic-mode half
  const uint32_t dcK = dc + 42u;         // fold +K1 into the counter offset
  const int dlog = ((D & (D - 1)) == 0) ? __builtin_ctz(D) : -1;

  // 256 wave-windows per sample; 4 waves per 256-thread block.
  const int range = NC - D;
  int wwin = (range > 0 ? (range + 255) / 256 : 512);
  wwin = (wwin + 511) & ~511;            // multiple of one 512-elem round
  const int WV = range > 0 ? (range + wwin - 1) / wwin : 0;
  const int GX = WV > 0 ? (WV + 3) / 4 : 1;

  // ws layout (u32): [aidx 64][wflag ns*64 padded lines]
  uint32_t* aidx = (uint32_t*)d_ws;
  uint32_t* wflag = aidx + 64;

  // node 1: zero the padded flags (graph memset node, stream-ordered)
  hipMemsetAsync(wflag, 0, (size_t)ns * 64 * sizeof(uint32_t), stream);
  // node 2: fused decide
  decide_kernel<<<dim3(GX, ns), 256, 0, stream>>>(
      ids, geto, probs, aidx, wflag, NC, D, dlog, dcK, wwin, WV);
  // node 3: select + gather
  int total = B * ns;
  gather_kernel<<<(total + 255) / 256, 256, 0, stream>>>(
      ids, adj, geto, aidx, wflag, out, B, D, ns);
}

// Round 11
// 44.733 us; speedup vs baseline: 1.0637x; 1.0637x over previous
//
#include <hip/hip_runtime.h>
#include <stdint.h>
#include <limits.h>

// ---------------------------------------------------------------------------
// GeToInformedNeighborSampler — round 11 (no memset node; 3 kernel nodes).
//
// Exact clip-aware reduction (validated rounds 5-10, absmax 0):
//   A = max_{j<D} v_j, a = first argmax   (v_j = gumbel(s*NC+j) + logp[j])
//   r[s] = (exists j in [D,NC): v_j > A) ? D-1 : a
//
// Round-10 lesson: the hipMemsetAsync graph node (6.4 KB!) costs ~41us —
// rocclr fillBufferAligned as a graph node is pathological. Kernel nodes are
// cheap (decide+gather ran in ~6.5us combined). So flags are zeroed by the
// phasea kernel again (r9 design, proven), and the graph has exactly three
// kernel nodes:
//   1. phasea_kernel  — per-sample A/a/kb + zero the padded flag line
//   2. witness_kernel — r9 scan: per-wave windows, best-candidate-first eval,
//                       poll-abort on a private 256B flag line, gated store
//   3. gather_kernel  — select (flag ? D-1 : a) folded in + output gather
//
// Flag determinism: set only on a true witness; abort only when already 1
// => final flag == [exists witness] exactly; phasea zeroes it every call
// (stream-ordered before witness) => graph-replay safe, no cross-call state.
// RNG (threefry2x32 key (0,42), classic split, o0-only) + raw-bits prune
// filter kb(A): unchanged (absmax 0, 9 consecutive rounds).
// All cross-kernel handoffs AGENT-scope (G16).
// ---------------------------------------------------------------------------

#define DEVI __device__ __forceinline__

DEVI uint32_t rotl32(uint32_t x, int n) { return (x << n) | (x >> (32 - n)); }

// threefry2x32-20, key (0,42), o0 only. x1 must already include +K1 (=42).
DEVI uint32_t tf_o0p(uint32_t x0, uint32_t x1) {
  const uint32_t K1 = 42u;
  const uint32_t K2 = 0x1BD11BDAu ^ K1;  // K0 = 0
#define TFR(r) x0 += x1; x1 = rotl32(x1, (r)); x1 ^= x0;
  TFR(13) TFR(15) TFR(26) TFR(6)
  x0 += K1; x1 += K2 + 1u;
  TFR(17) TFR(29) TFR(16) TFR(24)
  x0 += K2; x1 += 2u;                    // + K0 + 2
  TFR(13) TFR(15) TFR(26) TFR(6)
  /* x0 += K0 */ x1 += K1 + 3u;
  TFR(17) TFR(29) TFR(16) TFR(24)
  x0 += K1; x1 += K2 + 4u;
  TFR(13) TFR(15) TFR(26)
  x0 += x1;                              // round 20: only the add feeds o0
  x0 += K2;                              // final injection for o0
#undef TFR
  return x0;
}

DEVI uint32_t ld_dev_u32(const uint32_t* p) {
  return __hip_atomic_load(p, __ATOMIC_RELAXED, __HIP_MEMORY_SCOPE_AGENT);
}
DEVI void st_dev_u32(uint32_t* p, uint32_t v) {
  __hip_atomic_store(p, v, __ATOMIC_RELAXED, __HIP_MEMORY_SCOPE_AGENT);
}

// Raw-bits prune threshold: all j with g_j > m satisfy bits >= kb(m).
DEVI uint32_t prune_kb(float m) {
  float t = expf(-expf(-m)) - 1e-5f;
  if (!(t > 0.0f)) return 0u;
  uint32_t k = (uint32_t)ceilf(t * 8388608.0f);
  if (k > 8388607u) k = 8388607u;
  return k << 9;
}

// Exact JAX gumbel+logit value of element j of one sample.
DEVI float eval_v(uint32_t bits, uint32_t j,
                  const int* __restrict__ ids, const int* __restrict__ geto,
                  const float* __restrict__ probs, int D, int dlog) {
  float u = __uint_as_float((bits >> 9) | 0x3f800000u) - 1.0f;
  u = fmaxf(u, 1.17549435e-38f);
  float g = -logf(-logf(u));
  uint32_t b, d;
  if (dlog >= 0) { b = j >> dlog; d = j & (uint32_t)(D - 1); }
  else { b = j / (uint32_t)D; d = j - b * (uint32_t)D; }
  float lp = logf(probs[geto[(uint32_t)ids[b] * (uint32_t)D + d]]);
  return g + lp;
}

// ---- K1: phase A (max + first-argmax over j<D) + zero padded flag ---------
__global__ __launch_bounds__(64) void phasea_kernel(
    const int* __restrict__ ids, const int* __restrict__ geto,
    const float* __restrict__ probs,
    uint32_t* __restrict__ aidx, uint32_t* __restrict__ abits,
    uint32_t* __restrict__ kbv, uint32_t* __restrict__ wflag,
    int NC, int D, int dlog, uint32_t dcK) {
  const int s = blockIdx.x;
  const int lane = threadIdx.x;
  const uint32_t sbase = (uint32_t)s * (uint32_t)NC;

  float av = -INFINITY;
  int ai = INT_MAX;
  for (uint32_t j = (uint32_t)lane; j < (uint32_t)D; j += 64u) {
    uint32_t cc = sbase + j;
    float v = eval_v(tf_o0p(cc, cc + dcK), j, ids, geto, probs, D, dlog);
    if (v > av) { av = v; ai = (int)j; }   // ascending j: > keeps first
  }
  for (int off = 32; off > 0; off >>= 1) {
    float v2 = __shfl_xor(av, off);
    int i2 = __shfl_xor(ai, off);
    if (v2 > av || (v2 == av && i2 < ai)) { av = v2; ai = i2; }
  }
  if (lane == 0) {
    st_dev_u32(&aidx[s], (uint32_t)ai);
    st_dev_u32(&abits[s], __float_as_uint(av));
    st_dev_u32(&kbv[s], prune_kb(av));
    st_dev_u32(&wflag[s * 64], 0u);      // private 256B line, zeroed each call
  }
}

// ---- K2: per-wave-window witness scan with padded-flag abort --------------
__global__ __launch_bounds__(256) void witness_kernel(
    const int* __restrict__ ids, const int* __restrict__ geto,
    const float* __restrict__ probs,
    const uint32_t* __restrict__ abits, const uint32_t* __restrict__ kbv,
    uint32_t* __restrict__ wflag,
    int NC, int D, int dlog, uint32_t dcK, int wwin, int WV) {
  const int s = blockIdx.y;
  const int wv = blockIdx.x * 4 + (threadIdx.x >> 6);   // wave-window id
  const int lane = threadIdx.x & 63;
  if (wv >= WV) return;
  const uint32_t sbase = (uint32_t)s * (uint32_t)NC;
  uint32_t* flagp = &wflag[s * 64];

  const float A = __uint_as_float(ld_dev_u32(&abits[s]));
  const uint32_t kb = ld_dev_u32(&kbv[s]);

  uint32_t wstart = (uint32_t)D + (uint32_t)wv * (uint32_t)wwin;
  uint32_t wend = wstart + (uint32_t)wwin;
  if (wend > (uint32_t)NC) wend = (uint32_t)NC;

  for (uint32_t base = wstart; base < wend; base += 512u) {
    // Poll issued early (independent load), consumed at round end.
    uint32_t poll = 0u;
    if (lane == 0) poll = ld_dev_u32(flagp);

    uint32_t a[8];
    uint32_t bb = 0u, bj = 0xFFFFFFFFu;  // per-lane best passer
    bool anyok = false;
#pragma unroll
    for (int c = 0; c < 8; ++c) {
      uint32_t j = base + (uint32_t)(c * 64) + (uint32_t)lane;
      uint32_t cc = sbase + j;
      uint32_t bits = tf_o0p(cc, cc + dcK);
      a[c] = bits;
      bool ok = (bits >= kb) && (j < wend);
      if (ok) { anyok = true; if (bits > bb || bj == 0xFFFFFFFFu) { bb = bits; bj = j; } }
    }

    bool found = false;
    if (__any(anyok)) {
      // wave-reduce best candidate (max bits; index tie-break, deterministic)
      for (int off = 32; off > 0; off >>= 1) {
        uint32_t ob = __shfl_xor(bb, off);
        uint32_t oj = __shfl_xor(bj, off);
        bool better = (oj != 0xFFFFFFFFu) &&
                      (bj == 0xFFFFFFFFu || ob > bb || (ob == bb && oj < bj));
        if (better) { bb = ob; bj = oj; }
      }
      // Evaluate best candidate wave-uniform (broadcast loads, one chain).
      float v = eval_v(bb, bj, ids, geto, probs, D, dlog);
      if (v > A) {
        found = true;
      } else {
        // Rare fallback: evaluate every passer (exact round OR preserved).
#pragma unroll
        for (int c = 0; c < 8; ++c) {
          uint32_t j = base + (uint32_t)(c * 64) + (uint32_t)lane;
          if (a[c] >= kb && j < wend && j != bj) {
            if (eval_v(a[c], j, ids, geto, probs, D, dlog) > A) found = true;
          }
        }
      }
    }
    uint32_t p0 = (uint32_t)__shfl((int)poll, 0);
    if (__any(found)) {
      // plain agent store, gated: p0==1 => flag already 1 (monotonic), skip.
      if (lane == 0 && p0 == 0u) st_dev_u32(flagp, 1u);
      return;
    }
    if (p0) return;                      // someone already proved existence
  }
}

// ---- K3: select + gather outputs ------------------------------------------
__global__ __launch_bounds__(256) void gather_kernel(
    const int* __restrict__ ids, const int* __restrict__ adj,
    const int* __restrict__ geto,
    const uint32_t* __restrict__ aidx, const uint32_t* __restrict__ wflag,
    int* __restrict__ out, int B, int D, int ns) {
  __shared__ int sr[64];
  if (threadIdx.x < ns) {
    int s = threadIdx.x;
    int r = ld_dev_u32(&wflag[s * 64]) ? (D - 1) : (int)ld_dev_u32(&aidx[s]);
    r = r < 0 ? 0 : (r > D - 1 ? D - 1 : r);   // take(..., mode='clip')
    sr[s] = r;
  }
  __syncthreads();
  int t = blockIdx.x * blockDim.x + threadIdx.x;
  int total = B * ns;
  if (t >= total) return;
  int b = t / ns;
  int s = t - b * ns;
  int r = sr[s];
  int row = ids[b];
  out[t] = adj[row * D + r];            // weighted_adj[:, :ns]
  out[total + t] = geto[row * D + r];   // weighted_geto[:, :ns]
}

// ---------------------------------------------------------------------------
extern "C" void kernel_launch(void* const* d_in, const int* in_sizes, int n_in,
                              void* d_out, int out_size, void* d_ws, size_t ws_size,
                              hipStream_t stream) {
  const int* ids = (const int*)d_in[0];
  const int* adj = (const int*)d_in[2];
  const int* geto = (const int*)d_in[3];
  const float* probs = (const float*)d_in[4];
  int* out = (int*)d_out;

  const int B = in_sizes[0];             // 100000
  const int D = in_sizes[2] / B;         // 64
  const int NC = B * D;                  // 6.4M categories
  const int S = D;                       // 64 total samples (RESAMPLING_RATE=0)
  const int ns = out_size / (2 * B);     // 25 — only these are consumed
  const uint32_t dc = (uint32_t)(S / 2) * (uint32_t)NC;  // classic-mode half
  const uint32_t dcK = dc + 42u;         // fold +K1 into the counter offset
  const int dlog = ((D & (D - 1)) == 0) ? __builtin_ctz(D) : -1;

  // 256 wave-windows per sample; 4 waves per 256-thread block.
  const int range = NC - D;
  int wwin = (range > 0 ? (range + 255) / 256 : 512);
  wwin = (wwin + 511) & ~511;            // multiple of one 512-elem round
  const int WV = range > 0 ? (range + wwin - 1) / wwin : 0;
  const int GX = WV > 0 ? (WV + 3) / 4 : 1;

  // ws layout (u32): [aidx 64][abits 64][kbv 64][wflag ns*64 padded lines]
  uint32_t* aidx = (uint32_t*)d_ws;
  uint32_t* abits = aidx + 64;
  uint32_t* kbv = abits + 64;
  uint32_t* wflag = kbv + 64;

  phasea_kernel<<<ns, 64, 0, stream>>>(ids, geto, probs, aidx, abits, kbv,
                                       wflag, NC, D, dlog, dcK);
  witness_kernel<<<dim3(GX, ns), 256, 0, stream>>>(ids, geto, probs, abits,
                                                   kbv, wflag, NC, D, dlog,
                                                   dcK, wwin, WV);
  int total = B * ns;
  gather_kernel<<<(total + 255) / 256, 256, 0, stream>>>(
      ids, adj, geto, aidx, wflag, out, B, D, ns);
}

// Round 12
// 39.755 us; speedup vs baseline: 1.1969x; 1.1252x over previous
//
#include <hip/hip_runtime.h>
#include <stdint.h>
#include <limits.h>

// ---------------------------------------------------------------------------
// GeToInformedNeighborSampler — round 12 (lane-parallel candidate eval).
//
// Exact clip-aware reduction (validated rounds 5-11, absmax 0):
//   A = max_{j<D} v_j, a = first argmax   (v_j = gumbel(s*NC+j) + logp[j])
//   r[s] = (exists j in [D,NC): v_j > A) ? D-1 : a
//
// Round-11 diagnosis (arithmetic attribution): witness ~ 30us of the 44.7.
// Two causes fixed here, semantics unchanged:
//  1. SERIAL candidate evals: typical samples pass ~9 filter candidates per
//     512-round; the old best-candidate+fallback path evaluated them one
//     dependent ~1100cy gather chain at a time under exec-mask (~45% of
//     rounds hit the fallback). Now: ballot all passers, assign ordinals to
//     lanes, each lane RE-HASHES its candidate (no runtime-indexed reg
//     arrays -> no scratch) and evaluates CONCURRENTLY. One latency batch
//     per round (64-wide; loops if >64 passers, e.g. kb==0). The
//     existence-OR is order-independent => exact.
//  2. abits/kbv agent-load burst (12.8k loads to 2 lines at kernel start):
//     witness waves now recompute phase A in-registers (1 hash/lane +
//     shfl reduce ~ 1 round cost); the buffers are gone. phasea only
//     writes aidx and zeroes the padded flag lines.
//
// Flag discipline (r9, proven): per-sample flag on a private 256B line,
// plain AGENT store gated on the round's poll, poll-abort once per round.
// Final flag == [exists witness] exactly; zeroed every call by phasea.
// RNG (threefry2x32 key (0,42), classic split, o0-only) + raw-bits prune
// filter kb(A): unchanged (absmax 0, 10 consecutive rounds).
// ---------------------------------------------------------------------------

#define DEVI __device__ __forceinline__

DEVI uint32_t rotl32(uint32_t x, int n) { return (x << n) | (x >> (32 - n)); }

// threefry2x32-20, key (0,42), o0 only. x1 must already include +K1 (=42).
DEVI uint32_t tf_o0p(uint32_t x0, uint32_t x1) {
  const uint32_t K1 = 42u;
  const uint32_t K2 = 0x1BD11BDAu ^ K1;  // K0 = 0
#define TFR(r) x0 += x1; x1 = rotl32(x1, (r)); x1 ^= x0;
  TFR(13) TFR(15) TFR(26) TFR(6)
  x0 += K1; x1 += K2 + 1u;
  TFR(17) TFR(29) TFR(16) TFR(24)
  x0 += K2; x1 += 2u;                    // + K0 + 2
  TFR(13) TFR(15) TFR(26) TFR(6)
  /* x0 += K0 */ x1 += K1 + 3u;
  TFR(17) TFR(29) TFR(16) TFR(24)
  x0 += K1; x1 += K2 + 4u;
  TFR(13) TFR(15) TFR(26)
  x0 += x1;                              // round 20: only the add feeds o0
  x0 += K2;                              // final injection for o0
#undef TFR
  return x0;
}

DEVI uint32_t ld_dev_u32(const uint32_t* p) {
  return __hip_atomic_load(p, __ATOMIC_RELAXED, __HIP_MEMORY_SCOPE_AGENT);
}
DEVI void st_dev_u32(uint32_t* p, uint32_t v) {
  __hip_atomic_store(p, v, __ATOMIC_RELAXED, __HIP_MEMORY_SCOPE_AGENT);
}

// Raw-bits prune threshold: all j with g_j > m satisfy bits >= kb(m).
DEVI uint32_t prune_kb(float m) {
  float t = expf(-expf(-m)) - 1e-5f;
  if (!(t > 0.0f)) return 0u;
  uint32_t k = (uint32_t)ceilf(t * 8388608.0f);
  if (k > 8388607u) k = 8388607u;
  return k << 9;
}

// Exact JAX gumbel+logit value of element j of one sample.
DEVI float eval_v(uint32_t bits, uint32_t j,
                  const int* __restrict__ ids, const int* __restrict__ geto,
                  const float* __restrict__ probs, int D, int dlog) {
  float u = __uint_as_float((bits >> 9) | 0x3f800000u) - 1.0f;
  u = fmaxf(u, 1.17549435e-38f);
  float g = -logf(-logf(u));
  uint32_t b, d;
  if (dlog >= 0) { b = j >> dlog; d = j & (uint32_t)(D - 1); }
  else { b = j / (uint32_t)D; d = j - b * (uint32_t)D; }
  float lp = logf(probs[geto[(uint32_t)ids[b] * (uint32_t)D + d]]);
  return g + lp;
}

// In-wave phase A: returns A (all lanes) and first-argmax ai (all lanes).
DEVI void phase_a(const int* __restrict__ ids, const int* __restrict__ geto,
                  const float* __restrict__ probs,
                  uint32_t sbase, int D, int dlog, uint32_t dcK, int lane,
                  float& A, int& ai) {
  float av = -INFINITY;
  int aix = INT_MAX;
  for (uint32_t j = (uint32_t)lane; j < (uint32_t)D; j += 64u) {
    uint32_t cc = sbase + j;
    float v = eval_v(tf_o0p(cc, cc + dcK), j, ids, geto, probs, D, dlog);
    if (v > av) { av = v; aix = (int)j; }   // ascending j: > keeps first
  }
  for (int off = 32; off > 0; off >>= 1) {
    float v2 = __shfl_xor(av, off);
    int i2 = __shfl_xor(aix, off);
    if (v2 > av || (v2 == av && i2 < aix)) { av = v2; aix = i2; }
  }
  A = av; ai = aix;
}

// ---- K1: tiny phase-A writer + flag zero ----------------------------------
__global__ __launch_bounds__(64) void phasea_kernel(
    const int* __restrict__ ids, const int* __restrict__ geto,
    const float* __restrict__ probs,
    uint32_t* __restrict__ aidx, uint32_t* __restrict__ wflag,
    int NC, int D, int dlog, uint32_t dcK) {
  const int s = blockIdx.x;
  const uint32_t sbase = (uint32_t)s * (uint32_t)NC;
  float A; int ai;
  phase_a(ids, geto, probs, sbase, D, dlog, dcK, threadIdx.x, A, ai);
  if (threadIdx.x == 0) {
    st_dev_u32(&aidx[s], (uint32_t)ai);
    st_dev_u32(&wflag[s * 64], 0u);      // private 256B line, zeroed each call
  }
}

// ---- K2: witness scan, lane-parallel candidate evaluation -----------------
__global__ __launch_bounds__(256) void witness_kernel(
    const int* __restrict__ ids, const int* __restrict__ geto,
    const float* __restrict__ probs, uint32_t* __restrict__ wflag,
    int NC, int D, int dlog, uint32_t dcK, int wwin, int WV) {
  const int s = blockIdx.y;
  const int wv = blockIdx.x * 4 + (threadIdx.x >> 6);   // wave-window id
  const int lane = threadIdx.x & 63;
  if (wv >= WV) return;
  const uint32_t sbase = (uint32_t)s * (uint32_t)NC;
  uint32_t* flagp = &wflag[s * 64];

  // Phase A recomputed in-wave (kills the abits/kbv handoff burst).
  float A; int ai_unused;
  phase_a(ids, geto, probs, sbase, D, dlog, dcK, lane, A, ai_unused);
  const uint32_t kb = prune_kb(A);

  uint32_t wstart = (uint32_t)D + (uint32_t)wv * (uint32_t)wwin;
  uint32_t wend = wstart + (uint32_t)wwin;
  if (wend > (uint32_t)NC) wend = (uint32_t)NC;

  for (uint32_t base = wstart; base < wend; base += 512u) {
    // Poll issued early (independent load), consumed at round end.
    uint32_t poll = 0u;
    if (lane == 0) poll = ld_dev_u32(flagp);

    // Hash 8 chains; build per-lane pass mask only (no stored hash array).
    uint32_t pm = 0u;
#pragma unroll
    for (int c = 0; c < 8; ++c) {
      uint32_t j = base + (uint32_t)(c * 64) + (uint32_t)lane;
      uint32_t cc = sbase + j;
      uint32_t bits = tf_o0p(cc, cc + dcK);
      if (bits >= kb && j < wend) pm |= (1u << c);
    }

    bool found = false;
    if (__any(pm != 0u)) {
      // Ballot passers per chain slot; assign ordinals to lanes.
      unsigned long long bal0 = __ballot((pm >> 0) & 1u);
      unsigned long long bal1 = __ballot((pm >> 1) & 1u);
      unsigned long long bal2 = __ballot((pm >> 2) & 1u);
      unsigned long long bal3 = __ballot((pm >> 3) & 1u);
      unsigned long long bal4 = __ballot((pm >> 4) & 1u);
      unsigned long long bal5 = __ballot((pm >> 5) & 1u);
      unsigned long long bal6 = __ballot((pm >> 6) & 1u);
      unsigned long long bal7 = __ballot((pm >> 7) & 1u);
      int c0 = __popcll(bal0), c1 = __popcll(bal1), c2 = __popcll(bal2),
          c3 = __popcll(bal3), c4 = __popcll(bal4), c5 = __popcll(bal5),
          c6 = __popcll(bal6), c7 = __popcll(bal7);
      int b1 = c0, b2 = b1 + c1, b3 = b2 + c2, b4 = b3 + c3,
          b5 = b4 + c4, b6 = b5 + c5, b7 = b6 + c6, tot = b7 + c7;

      for (int ord0 = 0; ord0 < tot && !found; ord0 += 64) {
        int myord = ord0 + lane;
        float v = -INFINITY;
        if (myord < tot) {
          // Select chain slot + rank (all compile-time-indexed selects).
          int myc = 7, rank = myord - b7;
          unsigned long long m = bal7;
          if (myord < b1) { myc = 0; rank = myord;      m = bal0; }
          else if (myord < b2) { myc = 1; rank = myord - b1; m = bal1; }
          else if (myord < b3) { myc = 2; rank = myord - b2; m = bal2; }
          else if (myord < b4) { myc = 3; rank = myord - b3; m = bal3; }
          else if (myord < b5) { myc = 4; rank = myord - b4; m = bal4; }
          else if (myord < b6) { myc = 5; rank = myord - b5; m = bal5; }
          else if (myord < b7) { myc = 6; rank = myord - b6; m = bal6; }
          for (int i = 0; i < rank; ++i) m &= m - 1;   // rank-th set bit
          int src = __ffsll((unsigned long long)m) - 1;
          uint32_t j = base + (uint32_t)(myc * 64) + (uint32_t)src;
          uint32_t cc = sbase + j;
          uint32_t bits = tf_o0p(cc, cc + dcK);        // re-hash (cheap)
          v = eval_v(bits, j, ids, geto, probs, D, dlog);
        }
        if (__any(v > A)) found = true;   // all candidate chains in flight
      }
    }

    uint32_t p0 = (uint32_t)__shfl((int)poll, 0);
    if (found) {
      // plain agent store, gated: p0==1 => flag already 1 (monotonic), skip.
      if (lane == 0 && p0 == 0u) st_dev_u32(flagp, 1u);
      return;
    }
    if (p0) return;                      // someone already proved existence
  }
}

// ---- K3: select + gather outputs (grid-stride) ----------------------------
__global__ __launch_bounds__(256) void gather_kernel(
    const int* __restrict__ ids, const int* __restrict__ adj,
    const int* __restrict__ geto,
    const uint32_t* __restrict__ aidx, const uint32_t* __restrict__ wflag,
    int* __restrict__ out, int B, int D, int ns) {
  __shared__ int sr[64];
  if (threadIdx.x < ns) {
    int s = threadIdx.x;
    int r = ld_dev_u32(&wflag[s * 64]) ? (D - 1) : (int)ld_dev_u32(&aidx[s]);
    r = r < 0 ? 0 : (r > D - 1 ? D - 1 : r);   // take(..., mode='clip')
    sr[s] = r;
  }
  __syncthreads();
  int total = B * ns;
  int stride = gridDim.x * blockDim.x;
  for (int t = blockIdx.x * blockDim.x + threadIdx.x; t < total; t += stride) {
    int b = t / ns;
    int s = t - b * ns;
    int r = sr[s];
    int row = ids[b];
    out[t] = adj[row * D + r];            // weighted_adj[:, :ns]
    out[total + t] = geto[row * D + r];   // weighted_geto[:, :ns]
  }
}

// ---------------------------------------------------------------------------
extern "C" void kernel_launch(void* const* d_in, const int* in_sizes, int n_in,
                              void* d_out, int out_size, void* d_ws, size_t ws_size,
                              hipStream_t stream) {
  const int* ids = (const int*)d_in[0];
  const int* adj = (const int*)d_in[2];
  const int* geto = (const int*)d_in[3];
  const float* probs = (const float*)d_in[4];
  int* out = (int*)d_out;

  const int B = in_sizes[0];             // 100000
  const int D = in_sizes[2] / B;         // 64
  const int NC = B * D;                  // 6.4M categories
  const int S = D;                       // 64 total samples (RESAMPLING_RATE=0)
  const int ns = out_size / (2 * B);     // 25 — only these are consumed
  const uint32_t dc = (uint32_t)(S / 2) * (uint32_t)NC;  // classic-mode half
  const uint32_t dcK = dc + 42u;         // fold +K1 into the counter offset
  const int dlog = ((D & (D - 1)) == 0) ? __builtin_ctz(D) : -1;

  // 256 wave-windows per sample; 4 waves per 256-thread block.
  const int range = NC - D;
  int wwin = (range > 0 ? (range + 255) / 256 : 512);
  wwin = (wwin + 511) & ~511;            // multiple of one 512-elem round
  const int WV = range > 0 ? (range + wwin - 1) / wwin : 0;
  const int GX = WV > 0 ? (WV + 3) / 4 : 1;

  // ws layout (u32): [aidx 64][wflag ns*64 padded lines]
  uint32_t* aidx = (uint32_t*)d_ws;
  uint32_t* wflag = aidx + 64;

  phasea_kernel<<<ns, 64, 0, stream>>>(ids, geto, probs, aidx, wflag,
                                       NC, D, dlog, dcK);
  witness_kernel<<<dim3(GX, ns), 256, 0, stream>>>(ids, geto, probs, wflag,
                                                   NC, D, dlog, dcK, wwin, WV);
  int total = B * ns;
  int gblocks = (total + 255) / 256;
  if (gblocks > 2048) gblocks = 2048;
  gather_kernel<<<gblocks, 256, 0, stream>>>(
      ids, adj, geto, aidx, wflag, out, B, D, ns);
}